// Round 1
// baseline (59.183 us; speedup 1.0000x reference)
//
#include <hip/hip_runtime.h>

#define EPS 1e-8f

// Shapes fixed per reference: x [B=8, N=8192, D=512] fp32, scalar fp32 out.
#define B_DIM 8
#define N_DIM 8192
#define D_DIM 512

// K1: grid = B * chunksPerBatch blocks, 256 threads (4 waves).
// Each wave processes rowsPerWave consecutive rows; lane l owns d-slice [8l, 8l+8).
// Block writes one 512-float partial sum vector (sum of normalized rows).
__global__ __launch_bounds__(256) void k1_partial(const float* __restrict__ x,
                                                  float* __restrict__ partial,
                                                  int rowsPerChunk,
                                                  int chunksPerBatch) {
    const int blk   = blockIdx.x;
    const int b     = blk / chunksPerBatch;
    const int chunk = blk % chunksPerBatch;
    const int wave  = threadIdx.x >> 6;   // 0..3
    const int lane  = threadIdx.x & 63;
    const int rowsPerWave = rowsPerChunk >> 2;

    const long long rowStart = (long long)b * N_DIM
                             + (long long)chunk * rowsPerChunk
                             + (long long)wave * rowsPerWave;

    float acc[8];
    #pragma unroll
    for (int k = 0; k < 8; ++k) acc[k] = 0.0f;

    const float* base = x + rowStart * D_DIM + lane * 8;

    for (int r = 0; r < rowsPerWave; ++r) {
        const float4 v0 = *(const float4*)(base);
        const float4 v1 = *(const float4*)(base + 4);
        base += D_DIM;

        float ss = v0.x*v0.x + v0.y*v0.y + v0.z*v0.z + v0.w*v0.w
                 + v1.x*v1.x + v1.y*v1.y + v1.z*v1.z + v1.w*v1.w;
        // full 64-lane butterfly reduce
        #pragma unroll
        for (int off = 1; off < 64; off <<= 1)
            ss += __shfl_xor(ss, off);

        const float inv = 1.0f / fmaxf(sqrtf(ss), EPS);

        acc[0] += v0.x * inv; acc[1] += v0.y * inv;
        acc[2] += v0.z * inv; acc[3] += v0.w * inv;
        acc[4] += v1.x * inv; acc[5] += v1.y * inv;
        acc[6] += v1.z * inv; acc[7] += v1.w * inv;
    }

    // combine the 4 waves' partials deterministically via LDS
    __shared__ float lds[4][D_DIM];
    float* dst = &lds[wave][lane * 8];
    #pragma unroll
    for (int k = 0; k < 8; ++k) dst[k] = acc[k];
    __syncthreads();

    for (int d = threadIdx.x; d < D_DIM; d += 256) {
        float s = lds[0][d] + lds[1][d] + lds[2][d] + lds[3][d];
        partial[(long long)blk * D_DIM + d] = s;
    }
}

// K2: one block per batch, 512 threads (thread = one d). Sum partials over
// chunks, square, block-reduce to per-batch ||s||^2.
__global__ __launch_bounds__(512) void k2_batch(const float* __restrict__ partial,
                                                float* __restrict__ perBatch,
                                                int chunksPerBatch) {
    const int b = blockIdx.x;
    const int d = threadIdx.x;

    float s = 0.0f;
    const float* p = partial + (long long)b * chunksPerBatch * D_DIM + d;
    for (int c = 0; c < chunksPerBatch; ++c) s += p[(long long)c * D_DIM];

    float v = s * s;
    #pragma unroll
    for (int off = 1; off < 64; off <<= 1)
        v += __shfl_xor(v, off);

    __shared__ float lds[8];
    if ((threadIdx.x & 63) == 0) lds[threadIdx.x >> 6] = v;
    __syncthreads();
    if (threadIdx.x == 0) {
        float t = 0.0f;
        #pragma unroll
        for (int w = 0; w < 8; ++w) t += lds[w];
        perBatch[b] = t;
    }
}

// K3: final scalar.
__global__ void k3_final(const float* __restrict__ perBatch,
                         float* __restrict__ out) {
    if (threadIdx.x == 0 && blockIdx.x == 0) {
        float t = 0.0f;
        #pragma unroll
        for (int b = 0; b < B_DIM; ++b) t += perBatch[b];
        out[0] = t / ((float)N_DIM * (float)N_DIM * (float)B_DIM);
    }
}

extern "C" void kernel_launch(void* const* d_in, const int* in_sizes, int n_in,
                              void* d_out, int out_size, void* d_ws, size_t ws_size,
                              hipStream_t stream) {
    const float* x = (const float*)d_in[0];
    float* out = (float*)d_out;

    // Size the chunk count to the workspace: need B*chunks*512 floats for
    // partials + B floats for per-batch results.
    int chunks = 128;
    while (chunks > 1 &&
           ((size_t)B_DIM * chunks * D_DIM + B_DIM) * sizeof(float) > ws_size) {
        chunks >>= 1;
    }
    const int rowsPerChunk = N_DIM / chunks;

    float* partial  = (float*)d_ws;
    float* perBatch = partial + (size_t)B_DIM * chunks * D_DIM;

    k1_partial<<<dim3(B_DIM * chunks), dim3(256), 0, stream>>>(x, partial,
                                                               rowsPerChunk, chunks);
    k2_batch<<<dim3(B_DIM), dim3(512), 0, stream>>>(partial, perBatch, chunks);
    k3_final<<<dim3(1), dim3(64), 0, stream>>>(perBatch, out);
}